// Round 1
// baseline (107905.188 us; speedup 1.0000x reference)
//
#include <hip/hip_runtime.h>
#include <math.h>

#define B_   128
#define T_   512
#define V_   256
#define H_   512
#define G4_  2048  // 4*H

__device__ __forceinline__ float sigmoidf_(float x) {
    return 1.0f / (1.0f + __expf(-x));
}

__device__ __forceinline__ float dot4_(float4 a, float4 w, float s) {
    s = fmaf(a.x, w.x, s);
    s = fmaf(a.y, w.y, s);
    s = fmaf(a.z, w.z, s);
    s = fmaf(a.w, w.w, s);
    return s;
}

// One LSTM timestep: gates = x_t @ w_ih^T + h_prev @ w_hh^T + b_ih + b_hh,
// then elementwise cell update. Thread = one (b, j) pair, computes all 4 gates.
// Block = 256 threads: 16 j (fastest, coalesced writes) x 16 b.
// Grid = (H/16, B/16) = (32, 8) = 256 blocks.
template <int KIN, bool WRITE_OUT>
__global__ __launch_bounds__(256) void lstm_step(
    const float* __restrict__ xin,   // [B, T, KIN]
    const float* __restrict__ w_ih,  // [4H, KIN]
    const float* __restrict__ w_hh,  // [4H, H]
    const float* __restrict__ b_ih,  // [4H]
    const float* __restrict__ b_hh,  // [4H]
    const float* __restrict__ h_prev,// [B, H]
    float* __restrict__ h_next,      // [B, H]
    float* __restrict__ c,           // [B, H] (in/out)
    float* __restrict__ outbuf,      // [B, T, H] (layer-0 hidden sequence)
    int t)
{
    const int tid  = threadIdx.x;
    const int jsub = tid & 15;
    const int bsub = tid >> 4;
    const int j = blockIdx.x * 16 + jsub;
    const int b = blockIdx.y * 16 + bsub;

    const float4* __restrict__ xr = reinterpret_cast<const float4*>(xin + ((size_t)b * T_ + t) * KIN);
    const float4* __restrict__ hr = reinterpret_cast<const float4*>(h_prev + (size_t)b * H_);

    const int g0 = 0 * H_ + j;  // i
    const int g1 = 1 * H_ + j;  // f
    const int g2 = 2 * H_ + j;  // g
    const int g3 = 3 * H_ + j;  // o

    const float4* __restrict__ wi0 = reinterpret_cast<const float4*>(w_ih + (size_t)g0 * KIN);
    const float4* __restrict__ wi1 = reinterpret_cast<const float4*>(w_ih + (size_t)g1 * KIN);
    const float4* __restrict__ wi2 = reinterpret_cast<const float4*>(w_ih + (size_t)g2 * KIN);
    const float4* __restrict__ wi3 = reinterpret_cast<const float4*>(w_ih + (size_t)g3 * KIN);

    float a0 = 0.f, a1 = 0.f, a2 = 0.f, a3 = 0.f;

    #pragma unroll 8
    for (int k = 0; k < KIN / 4; ++k) {
        float4 a = xr[k];
        a0 = dot4_(a, wi0[k], a0);
        a1 = dot4_(a, wi1[k], a1);
        a2 = dot4_(a, wi2[k], a2);
        a3 = dot4_(a, wi3[k], a3);
    }

    const float4* __restrict__ wh0 = reinterpret_cast<const float4*>(w_hh + (size_t)g0 * H_);
    const float4* __restrict__ wh1 = reinterpret_cast<const float4*>(w_hh + (size_t)g1 * H_);
    const float4* __restrict__ wh2 = reinterpret_cast<const float4*>(w_hh + (size_t)g2 * H_);
    const float4* __restrict__ wh3 = reinterpret_cast<const float4*>(w_hh + (size_t)g3 * H_);

    #pragma unroll 8
    for (int k = 0; k < H_ / 4; ++k) {
        float4 a = hr[k];
        a0 = dot4_(a, wh0[k], a0);
        a1 = dot4_(a, wh1[k], a1);
        a2 = dot4_(a, wh2[k], a2);
        a3 = dot4_(a, wh3[k], a3);
    }

    a0 += b_ih[g0] + b_hh[g0];
    a1 += b_ih[g1] + b_hh[g1];
    a2 += b_ih[g2] + b_hh[g2];
    a3 += b_ih[g3] + b_hh[g3];

    const float ig = sigmoidf_(a0);
    const float fg = sigmoidf_(a1);
    const float gg = tanhf(a2);
    const float og = sigmoidf_(a3);

    const size_t idx = (size_t)b * H_ + j;
    const float cn = fg * c[idx] + ig * gg;
    c[idx] = cn;
    const float hn = og * tanhf(cn);
    h_next[idx] = hn;
    if (WRITE_OUT) {
        outbuf[((size_t)b * T_ + t) * H_ + j] = hn;
    }
}

// logits[b, v] = dot(h1_final[b, :], fc_w[v, :]) + fc_b[v]
__global__ __launch_bounds__(256) void logits_kernel(
    const float* __restrict__ h1,    // [B, H] final hidden of layer 1
    const float* __restrict__ fc_w,  // [V, H]
    const float* __restrict__ fc_b,  // [V]
    float* __restrict__ out)         // [B, V] at d_out offset 0
{
    __shared__ float hs[H_];
    const int b = blockIdx.x;
    for (int k = threadIdx.x; k < H_; k += 256) hs[k] = h1[(size_t)b * H_ + k];
    __syncthreads();

    const int v = threadIdx.x;  // V_ == 256 == blockDim
    const float4* __restrict__ wr = reinterpret_cast<const float4*>(fc_w + (size_t)v * H_);
    const float4* __restrict__ hr = reinterpret_cast<const float4*>(hs);
    float s = 0.f;
    #pragma unroll 8
    for (int k = 0; k < H_ / 4; ++k) s = dot4_(hr[k], wr[k], s);
    out[(size_t)b * V_ + v] = s + fc_b[v];
}

// Copy final h/c states into d_out tail: layout logits | h_n[2,B,H] | c_n[2,B,H]
__global__ __launch_bounds__(256) void copy_states(
    const float* __restrict__ h0f, const float* __restrict__ h1f,
    const float* __restrict__ c0,  const float* __restrict__ c1,
    float* __restrict__ out)
{
    const int i = blockIdx.x * 256 + threadIdx.x;  // 0 .. B*H-1
    const int NBH = B_ * H_;
    float* base = out + (size_t)B_ * V_;
    base[i]            = h0f[i];
    base[NBH + i]      = h1f[i];
    base[2 * NBH + i]  = c0[i];
    base[3 * NBH + i]  = c1[i];
}

extern "C" void kernel_launch(void* const* d_in, const int* in_sizes, int n_in,
                              void* d_out, int out_size, void* d_ws, size_t ws_size,
                              hipStream_t stream) {
    const float* x     = (const float*)d_in[0];
    const float* w_ih0 = (const float*)d_in[1];
    const float* w_hh0 = (const float*)d_in[2];
    const float* b_ih0 = (const float*)d_in[3];
    const float* b_hh0 = (const float*)d_in[4];
    const float* w_ih1 = (const float*)d_in[5];
    const float* w_hh1 = (const float*)d_in[6];
    const float* b_ih1 = (const float*)d_in[7];
    const float* b_hh1 = (const float*)d_in[8];
    const float* fc_w  = (const float*)d_in[9];
    const float* fc_b  = (const float*)d_in[10];
    float* out = (float*)d_out;

    // Workspace layout (floats):
    float* ws   = (float*)d_ws;
    float* out0 = ws;                                // [B,T,H] = 33,554,432 floats
    float* h0a  = out0 + (size_t)B_ * T_ * H_;       // [B,H]
    float* h0b  = h0a + B_ * H_;
    float* c0   = h0b + B_ * H_;
    float* h1a  = c0  + B_ * H_;
    float* h1b  = h1a + B_ * H_;
    float* c1   = h1b + B_ * H_;
    // total: 33,554,432 + 6*65,536 floats ~= 130 MB

    // Zero initial h and c (harness poisons ws with 0xAA once; graph replays
    // re-run this memset so state is deterministic per call).
    hipMemsetAsync(h0a, 0, (size_t)6 * B_ * H_ * sizeof(float), stream);

    dim3 blk(256);
    dim3 grd(H_ / 16, B_ / 16);  // 32 x 8 = 256 blocks

    // Layer 0: x [B,T,V] -> out0 [B,T,H]
    for (int t = 0; t < T_; ++t) {
        const float* hp = (t & 1) ? h0b : h0a;
        float*       hn = (t & 1) ? h0a : h0b;
        lstm_step<V_, true><<<grd, blk, 0, stream>>>(
            x, w_ih0, w_hh0, b_ih0, b_hh0, hp, hn, c0, out0, t);
    }
    // Layer 1: out0 [B,T,H] -> final h1/c1 only
    for (int t = 0; t < T_; ++t) {
        const float* hp = (t & 1) ? h1b : h1a;
        float*       hn = (t & 1) ? h1a : h1b;
        lstm_step<H_, false><<<grd, blk, 0, stream>>>(
            out0, w_ih1, w_hh1, b_ih1, b_hh1, hp, hn, c1, nullptr, t);
    }
    // T is even -> final h in the 'a' buffers.
    logits_kernel<<<B_, 256, 0, stream>>>(h1a, fc_w, fc_b, out);
    copy_states<<<(B_ * H_) / 256, 256, 0, stream>>>(h0a, h1a, c0, c1, out);
}

// Round 2
// 5455.230 us; speedup vs baseline: 19.7801x; 19.7801x over previous
//
#include <hip/hip_runtime.h>
#include <math.h>

#define B_ 128
#define T_ 512
#define V_ 256
#define H_ 512

typedef unsigned short u16;
typedef __attribute__((ext_vector_type(8))) __bf16 bf16x8;
typedef __attribute__((ext_vector_type(4))) float f32x4;

__device__ __forceinline__ float sigf(float x) { return 1.f / (1.f + __expf(-x)); }
__device__ __forceinline__ float tanh_fast(float x) {
    x = fminf(fmaxf(x, -15.f), 15.f);
    float e = __expf(2.f * x);
    return (e - 1.f) / (e + 1.f);
}
__device__ __forceinline__ u16 f2bf(float f) {
    union { float f; unsigned int u; } v; v.f = f;
    unsigned int r = v.u + 0x7FFFu + ((v.u >> 16) & 1u);
    return (u16)(r >> 16);
}

// ---------- prep kernels (once per call, cheap) ----------

// x [B,T,V] f32 -> Xswz[t][mt][kc][lane][8] bf16  (A-fragment order)
__global__ __launch_bounds__(256) void conv_x(u16* __restrict__ dst, const float* __restrict__ x) {
    int tid = blockIdx.x * 256 + threadIdx.x;       // B*T*V = 16,777,216
    int k = tid & (V_ - 1);
    int t = (tid >> 8) & (T_ - 1);
    int b = tid >> 17;
    float v = x[tid];
    int lane = (b & 15) | (((k >> 3) & 3) << 4);
    dst[((((size_t)t * 8 + (b >> 4)) * 8) + (k >> 5)) * 512 + (size_t)lane * 8 + (k & 7)] = f2bf(v);
}

// [w_ih | w_hh] -> WB[ntile][kc][lane][8] bf16  (B-fragment order)
__global__ __launch_bounds__(256) void conv_w(u16* __restrict__ dst,
                                              const float* __restrict__ wih,
                                              const float* __restrict__ whh,
                                              int KIN, int Ktot) {
    int tid = blockIdx.x * 256 + threadIdx.x;       // 2048 * Ktot
    int n = tid / Ktot, k = tid - n * Ktot;
    float v = (k < KIN) ? wih[(size_t)n * KIN + k] : whh[(size_t)n * H_ + (k - KIN)];
    int lane = (n & 15) | (((k >> 3) & 3) << 4);
    dst[((size_t)((n >> 4) * (Ktot >> 5) + (k >> 5))) * 512 + (size_t)lane * 8 + (k & 7)] = f2bf(v);
}

__global__ __launch_bounds__(256) void vadd(float* __restrict__ d,
                                            const float* __restrict__ a,
                                            const float* __restrict__ b, int n) {
    int i = blockIdx.x * 256 + threadIdx.x;
    if (i < n) d[i] = a[i] + b[i];
}

// ---------- fused per-step kernel: layer0 @ t=s (wg<64), layer1 @ t=s-1 (wg>=64) ----------
// Wave (wg,wv) owns m-tile mt (16 b's) x j-slice js (16 hidden) x 4 gate types.
__global__ __launch_bounds__(256) void step_fused(
    const u16* __restrict__ Xswz, u16* __restrict__ Out0swz,
    const u16* __restrict__ WB0, const u16* __restrict__ WB1,
    const float* __restrict__ bsum0, const float* __restrict__ bsum1,
    const u16* __restrict__ H0in, u16* __restrict__ H0out,
    const u16* __restrict__ H1in, u16* __restrict__ H1out,
    float* __restrict__ c0, float* __restrict__ c1,
    float* __restrict__ h0p, float* __restrict__ h1p,
    int s)
{
    const int wg = blockIdx.x;
    const int wv = threadIdx.x >> 6;
    const int lane = threadIdx.x & 63;
    const bool is1 = wg >= 64;
    if (is1 ? (s == 0) : (s == T_)) return;
    const int wgl = is1 ? wg - 64 : wg;
    const int t = is1 ? s - 1 : s;

    const int js = wgl >> 1;                 // 0..31 -> hidden slice js*16..+15
    const int mt = ((wgl & 1) << 2) | wv;    // 0..7  -> batch tile mt*16..+15

    const int KCIN = is1 ? 16 : 8;
    const int KCtot = KCIN + 16;
    const u16* Ain  = is1 ? (Out0swz + (size_t)t * (8 * 16 * 512))
                          : (Xswz    + (size_t)t * (8 * 8 * 512));
    const u16* Hin  = is1 ? H1in : H0in;
    const u16* WB   = is1 ? WB1 : WB0;
    const float* bsum = is1 ? bsum1 : bsum0;

    const u16* arow = Ain + (size_t)mt * KCIN * 512 + (size_t)lane * 8;
    const u16* hrow = Hin + (size_t)mt * 16 * 512 + (size_t)lane * 8;
    const u16* w0 = WB + ((size_t)(js)       * KCtot) * 512 + (size_t)lane * 8;
    const u16* w1 = WB + ((size_t)(32 + js)  * KCtot) * 512 + (size_t)lane * 8;
    const u16* w2 = WB + ((size_t)(64 + js)  * KCtot) * 512 + (size_t)lane * 8;
    const u16* w3 = WB + ((size_t)(96 + js)  * KCtot) * 512 + (size_t)lane * 8;

    f32x4 ai = {0.f, 0.f, 0.f, 0.f}, af = ai, ag = ai, ao = ai;

    #pragma unroll 4
    for (int kc = 0; kc < KCIN; ++kc) {
        bf16x8 a  = *(const bf16x8*)(arow + (size_t)kc * 512);
        bf16x8 b0 = *(const bf16x8*)(w0 + (size_t)kc * 512);
        bf16x8 b1 = *(const bf16x8*)(w1 + (size_t)kc * 512);
        bf16x8 b2 = *(const bf16x8*)(w2 + (size_t)kc * 512);
        bf16x8 b3 = *(const bf16x8*)(w3 + (size_t)kc * 512);
        ai = __builtin_amdgcn_mfma_f32_16x16x32_bf16(a, b0, ai, 0, 0, 0);
        af = __builtin_amdgcn_mfma_f32_16x16x32_bf16(a, b1, af, 0, 0, 0);
        ag = __builtin_amdgcn_mfma_f32_16x16x32_bf16(a, b2, ag, 0, 0, 0);
        ao = __builtin_amdgcn_mfma_f32_16x16x32_bf16(a, b3, ao, 0, 0, 0);
    }
    #pragma unroll 4
    for (int kc = 0; kc < 16; ++kc) {
        bf16x8 a  = *(const bf16x8*)(hrow + (size_t)kc * 512);
        bf16x8 b0 = *(const bf16x8*)(w0 + (size_t)(KCIN + kc) * 512);
        bf16x8 b1 = *(const bf16x8*)(w1 + (size_t)(KCIN + kc) * 512);
        bf16x8 b2 = *(const bf16x8*)(w2 + (size_t)(KCIN + kc) * 512);
        bf16x8 b3 = *(const bf16x8*)(w3 + (size_t)(KCIN + kc) * 512);
        ai = __builtin_amdgcn_mfma_f32_16x16x32_bf16(a, b0, ai, 0, 0, 0);
        af = __builtin_amdgcn_mfma_f32_16x16x32_bf16(a, b1, af, 0, 0, 0);
        ag = __builtin_amdgcn_mfma_f32_16x16x32_bf16(a, b2, ag, 0, 0, 0);
        ao = __builtin_amdgcn_mfma_f32_16x16x32_bf16(a, b3, ao, 0, 0, 0);
    }

    // C/D layout: col = lane&15 (hidden j), row = (lane>>4)*4 + reg (batch b)
    const int jl = (js << 4) | (lane & 15);
    const int bb = (mt << 4) | ((lane >> 4) << 2);
    const float bi = bsum[jl], bfb = bsum[512 + jl], bgb = bsum[1024 + jl], bob = bsum[1536 + jl];
    float* c  = is1 ? c1 : c0;
    float* hp = is1 ? h1p : h0p;
    u16* Hout = is1 ? H1out : H0out;

    #pragma unroll
    for (int r = 0; r < 4; ++r) {
        const int b = bb + r;
        const float vi = sigf(ai[r] + bi);
        const float vf = sigf(af[r] + bfb);
        const float vg = tanh_fast(ag[r] + bgb);
        const float vo = sigf(ao[r] + bob);
        const size_t ci = (size_t)b * H_ + jl;
        const float cn = vf * c[ci] + vi * vg;
        c[ci] = cn;
        const float hn = vo * tanh_fast(cn);
        hp[ci] = hn;
        const u16 hb = f2bf(hn);
        // swizzled-h position for next step's A-operand
        const size_t so = ((size_t)(mt * 16 + (jl >> 5))) * 512
                        + (size_t)((b & 15) | (((jl >> 3) & 3) << 4)) * 8 + (jl & 7);
        Hout[so] = hb;
        if (!is1) Out0swz[(size_t)t * (8 * 16 * 512) + so] = hb;
    }
}

// ---------- tail kernels ----------
__device__ __forceinline__ float dot4_(float4 a, float4 w, float s) {
    s = fmaf(a.x, w.x, s); s = fmaf(a.y, w.y, s);
    s = fmaf(a.z, w.z, s); s = fmaf(a.w, w.w, s);
    return s;
}

__global__ __launch_bounds__(256) void logits_kernel(
    const float* __restrict__ h1, const float* __restrict__ fc_w,
    const float* __restrict__ fc_b, float* __restrict__ out)
{
    __shared__ float hs[H_];
    const int b = blockIdx.x;
    for (int k = threadIdx.x; k < H_; k += 256) hs[k] = h1[(size_t)b * H_ + k];
    __syncthreads();
    const int v = threadIdx.x;
    const float4* wr = reinterpret_cast<const float4*>(fc_w + (size_t)v * H_);
    const float4* hr = reinterpret_cast<const float4*>(hs);
    float s = 0.f;
    #pragma unroll 8
    for (int k = 0; k < H_ / 4; ++k) s = dot4_(hr[k], wr[k], s);
    out[(size_t)b * V_ + v] = s + fc_b[v];
}

__global__ __launch_bounds__(256) void copy_states(
    const float* __restrict__ h0f, const float* __restrict__ h1f,
    const float* __restrict__ c0, const float* __restrict__ c1,
    float* __restrict__ out)
{
    const int i = blockIdx.x * 256 + threadIdx.x;
    const int NBH = B_ * H_;
    float* base = out + (size_t)B_ * V_;
    base[i] = h0f[i];
    base[NBH + i] = h1f[i];
    base[2 * NBH + i] = c0[i];
    base[3 * NBH + i] = c1[i];
}

extern "C" void kernel_launch(void* const* d_in, const int* in_sizes, int n_in,
                              void* d_out, int out_size, void* d_ws, size_t ws_size,
                              hipStream_t stream) {
    const float* x     = (const float*)d_in[0];
    const float* w_ih0 = (const float*)d_in[1];
    const float* w_hh0 = (const float*)d_in[2];
    const float* b_ih0 = (const float*)d_in[3];
    const float* b_hh0 = (const float*)d_in[4];
    const float* w_ih1 = (const float*)d_in[5];
    const float* w_hh1 = (const float*)d_in[6];
    const float* b_ih1 = (const float*)d_in[7];
    const float* b_hh1 = (const float*)d_in[8];
    const float* fc_w  = (const float*)d_in[9];
    const float* fc_b  = (const float*)d_in[10];
    float* out = (float*)d_out;

    // ---- workspace carve-up (bytes) ----
    char* p = (char*)d_ws;
    u16* Xswz    = (u16*)p; p += (size_t)512 * 8 * 8 * 512 * 2;    // 32 MB
    u16* Out0swz = (u16*)p; p += (size_t)512 * 8 * 16 * 512 * 2;   // 64 MB
    u16* WB0     = (u16*)p; p += (size_t)128 * 24 * 512 * 2;       // 3 MB
    u16* WB1     = (u16*)p; p += (size_t)128 * 32 * 512 * 2;       // 4 MB
    u16* H0a     = (u16*)p; p += 8 * 16 * 512 * 2;                 // 128 KB
    u16* H1a     = (u16*)p; p += 8 * 16 * 512 * 2;
    u16* H0b     = (u16*)p; p += 8 * 16 * 512 * 2;
    u16* H1b     = (u16*)p; p += 8 * 16 * 512 * 2;
    float* c0    = (float*)p; p += (size_t)B_ * H_ * 4;
    float* c1    = (float*)p; p += (size_t)B_ * H_ * 4;
    float* bsum0 = (float*)p; p += 2048 * 4;
    float* bsum1 = (float*)p; p += 2048 * 4;
    float* h0p   = (float*)p; p += (size_t)B_ * H_ * 4;
    float* h1p   = (float*)p; p += (size_t)B_ * H_ * 4;

    // ---- init + operand re-layout ----
    hipMemsetAsync(H0a, 0, 2 * 8 * 16 * 512 * 2, stream);          // H0a+H1a (t=0 inputs)
    hipMemsetAsync(c0, 0, 2 * (size_t)B_ * H_ * 4, stream);        // c0+c1
    conv_x<<<65536, 256, 0, stream>>>(Xswz, x);
    conv_w<<<(2048 * 768) / 256, 256, 0, stream>>>(WB0, w_ih0, w_hh0, 256, 768);
    conv_w<<<(2048 * 1024) / 256, 256, 0, stream>>>(WB1, w_ih1, w_hh1, 512, 1024);
    vadd<<<8, 256, 0, stream>>>(bsum0, b_ih0, b_hh0, 2048);
    vadd<<<8, 256, 0, stream>>>(bsum1, b_ih1, b_hh1, 2048);

    // ---- pipelined recurrence: layer0 @ s, layer1 @ s-1 ----
    for (int s = 0; s <= T_; ++s) {
        const u16* H0in = (s & 1) ? H0b : H0a;
        u16*       H0out = (s & 1) ? H0a : H0b;
        const u16* H1in = (s & 1) ? H1a : H1b;   // parity of t-1 = s-1
        u16*       H1out = (s & 1) ? H1b : H1a;
        step_fused<<<128, 256, 0, stream>>>(
            Xswz, Out0swz, WB0, WB1, bsum0, bsum1,
            H0in, H0out, H1in, H1out, c0, c1, h0p, h1p, s);
    }

    logits_kernel<<<B_, 256, 0, stream>>>(h1p, fc_w, fc_b, out);
    copy_states<<<(B_ * H_) / 256, 256, 0, stream>>>(h0p, h1p, c0, c1, out);
}